// Round 14
// baseline (21633.630 us; speedup 1.0000x reference)
//
#include <hip/hip_runtime.h>

#define HS   512
#define LNUM 4
#define TT   128
#define MMEM 2048
#define FFD  2048
#define NB   256
#define NT   512
#define INV512 (1.0f/512.0f)
#define QSCALE 0.08838834764831845f  // 1/sqrt(128)

typedef unsigned short ushortt;

// ---------------- workspace layout (float offsets) ----------------
constexpr size_t KHALF = (size_t)LNUM*MMEM*HS/2;
constexpr size_t HHALF = (size_t)LNUM*HS*HS/2;
constexpr size_t FHALF = (size_t)LNUM*FFD*HS/2;
constexpr size_t GHALF = (size_t)LNUM*3*HS*HS/2;
constexpr size_t OFF_KBF    = 0;
constexpr size_t OFF_VBF    = OFF_KBF    + KHALF;   // V transposed [l][f][m]
constexpr size_t OFF_WCOMBBF= OFF_VBF    + KHALF;
constexpr size_t OFF_WQP    = OFF_WCOMBBF+ HHALF;   // packed [l][b][f][16]
constexpr size_t OFF_W2P    = OFF_WQP    + HHALF;   // packed [l][bid][f][8]
constexpr size_t OFF_FFW1BF = OFF_W2P    + FHALF;
constexpr size_t OFF_CAWOBF = OFF_FFW1BF + FHALF;
constexpr size_t OFF_WXBF   = OFF_CAWOBF + HHALF;   // bf16 Wx [l][g][f][e]
constexpr size_t OFF_WHBF   = OFF_WXBF   + GHALF;   // bf16 Wh
constexpr size_t OFF_CSA    = OFF_WHBF   + GHALF;
constexpr size_t OFF_SQ     = OFF_CSA    + (size_t)LNUM*HS;
constexpr size_t OFF_CBQ    = OFF_SQ     + (size_t)LNUM*HS;
// mutable (memset 0)
constexpr size_t OFF_STATE = OFF_CBQ   + (size_t)LNUM*HS;
constexpr size_t OFF_H     = OFF_STATE;                           // [2][4][512]
constexpr size_t OFF_C     = OFF_H     + 2*LNUM*HS;
constexpr size_t OFF_XING  = OFF_C     + 2*LNUM*HS;               // 512
constexpr size_t OFF_Z1    = OFF_XING  + HS;                      // 512
constexpr size_t OFF_Z02   = OFF_Z1    + HS;                      // [2][1024] parity
constexpr size_t OFF_T2G   = OFF_Z02   + 2*2*HS;                  // 512
constexpr size_t OFF_YP    = OFF_T2G   + HS;                      // [32][512] owner
constexpr size_t OFF_Y2P   = OFF_YP    + 32*HS;                   // [64][512] 4-way
constexpr size_t OFF_CTXP  = OFF_Y2P   + 64*HS;                   // [128][128] owner
constexpr size_t OFF_DENS  = OFF_CTXP  + 128*128;                 // 128 slots
constexpr size_t OFF_S1S   = OFF_DENS  + 128;                     // 32*2 slots
constexpr size_t OFF_S2S   = OFF_S1S   + 64;                      // 32*2 slots
constexpr size_t OFF_J1    = OFF_S2S   + 64;                      // 64*32 u32
constexpr size_t OFF_J2    = OFF_J1    + 64*32;                   // 128*32 u32
constexpr size_t OFF_XFL   = OFF_J2    + 128*32;                  // 4*32 u32
constexpr size_t OFF_FLAGS = OFF_XFL   + 4*32;                    // NB*32 u32
constexpr size_t WS_TOTAL  = OFF_FLAGS + (size_t)NB*32;

__device__ __forceinline__ float wred(float v) {
#pragma unroll
  for (int m = 32; m; m >>= 1) v += __shfl_xor(v, m);
  return v;
}
__device__ __forceinline__ float sigm(float x) { return 1.0f/(1.0f+__expf(-x)); }
__device__ __forceinline__ ushortt f2bf(float f) {
  unsigned u = __float_as_uint(f);
  return (ushortt)((u + 0x7fffu + ((u >> 16) & 1u)) >> 16);
}
__device__ __forceinline__ float bflo(unsigned v){ return __uint_as_float(v << 16); }
__device__ __forceinline__ float bfhi(unsigned v){ return __uint_as_float(v & 0xffff0000u); }
__device__ __forceinline__ void ld8bfp(const ushortt* p, unsigned* d) {
  uint4 v = *(const uint4*)p;
  d[0] = v.x; d[1] = v.y; d[2] = v.z; d[3] = v.w;
}

__device__ __forceinline__ float ald(const float* p) {
  return __hip_atomic_load(p, __ATOMIC_RELAXED, __HIP_MEMORY_SCOPE_AGENT);
}
__device__ __forceinline__ void ast(float* p, float v) {
  __hip_atomic_store(p, v, __ATOMIC_RELAXED, __HIP_MEMORY_SCOPE_AGENT);
}
__device__ __forceinline__ unsigned aldu(const unsigned* p) {
  return __hip_atomic_load(p, __ATOMIC_RELAXED, __HIP_MEMORY_SCOPE_AGENT);
}
__device__ __forceinline__ void astu(unsigned* p, unsigned v) {
  __hip_atomic_store(p, v, __ATOMIC_RELAXED, __HIP_MEMORY_SCOPE_AGENT);
}

template <class F>
__device__ __forceinline__ void barrier_pf(unsigned* flags, unsigned g, F&& pf) {
  asm volatile("s_waitcnt vmcnt(0)" ::: "memory");
  __syncthreads();
  if (threadIdx.x == 0) astu(flags + (size_t)blockIdx.x*32, g);
  pf();
  if (threadIdx.x < NB) {
    const unsigned* f = flags + (size_t)threadIdx.x*32;
    while ((int)(aldu(f) - g) < 0) __builtin_amdgcn_s_sleep(2);
  }
  __syncthreads();
}
__device__ __forceinline__ void jflag(unsigned* J, int id, unsigned val) {
  asm volatile("s_waitcnt vmcnt(0)" ::: "memory");
  __syncthreads();
  if (threadIdx.x == 0) astu(J + (size_t)id*32, val);
}
__device__ __forceinline__ void jwait(unsigned* J, int n, unsigned val) {
  if (threadIdx.x < n) {
    const unsigned* f = J + (size_t)threadIdx.x*32;
    while ((int)(aldu(f) - val) < 0) __builtin_amdgcn_s_sleep(1);
  }
  __syncthreads();
}
__device__ __forceinline__ void slotred32(const float* slots, float* sh, int o,
                                          int w, int lane) {
  if (w == 0) {
    float a = (lane < 32) ? ald(slots + lane*2) : ald(slots + (lane-32)*2 + 1);
#pragma unroll
    for (int m = 16; m; m >>= 1) a += __shfl_xor(a, m);
    if (lane == 0)  sh[o]   = a;
    if (lane == 32) sh[o+1] = a;
  }
}

// ---------------- precompute kernels ----------------

__global__ __launch_bounds__(256) void kv_gemm(
    const float* __restrict__ hist, const float* __restrict__ caWin,
    const float* __restrict__ caBin, ushortt* __restrict__ out, int koff, int vt) {
  __shared__ float As[16][64];
  __shared__ float Bs[16][64];
  const int l = blockIdx.z, m0 = blockIdx.x*64, f0 = blockIdx.y*64;
  const int tid = threadIdx.x, tm = tid >> 4, tf = tid & 15;
  float acc[4][4] = {};
  for (int e0 = 0; e0 < HS; e0 += 16) {
#pragma unroll
    for (int it = 0; it < 4; ++it) {
      int idx = tid + it*256, k = idx & 15, mm = idx >> 4;
      As[k][mm] = hist[((size_t)(m0+mm)*LNUM + l)*HS + e0 + k];
      Bs[k][mm] = caWin[((size_t)l*(3*HS) + koff + f0 + mm)*HS + e0 + k];
    }
    __syncthreads();
#pragma unroll
    for (int k = 0; k < 16; ++k) {
      float a[4], b[4];
#pragma unroll
      for (int xx = 0; xx < 4; ++xx) { a[xx] = As[k][tm*4+xx]; b[xx] = Bs[k][tf*4+xx]; }
#pragma unroll
      for (int xx = 0; xx < 4; ++xx)
#pragma unroll
        for (int y = 0; y < 4; ++y) acc[xx][y] += a[xx]*b[y];
    }
    __syncthreads();
  }
#pragma unroll
  for (int xx = 0; xx < 4; ++xx)
#pragma unroll
    for (int y = 0; y < 4; ++y) {
      int m = m0 + tm*4 + xx, f = f0 + tf*4 + y;
      ushortt v = f2bf(acc[xx][y] + caBin[l*(3*HS) + koff + f]);
      if (vt) out[(size_t)l*MMEM*HS + (size_t)f*MMEM + m] = v;
      else    out[((size_t)l*MMEM + m)*HS + f] = v;
    }
}

__global__ __launch_bounds__(256) void wcomb_gemm(
    const float* __restrict__ saWo, const float* __restrict__ saWin,
    ushortt* __restrict__ wcomb) {
  __shared__ float As[16][64];
  __shared__ float Bs[16][64];
  const int l = blockIdx.z, f0 = blockIdx.x*64, j0 = blockIdx.y*64;
  const int tid = threadIdx.x, tm = tid >> 4, tf = tid & 15;
  float acc[4][4] = {};
  for (int e0 = 0; e0 < HS; e0 += 16) {
#pragma unroll
    for (int it = 0; it < 4; ++it) {
      int idx = tid + it*256;
      { int k = idx & 15, ff = idx >> 4;
        As[k][ff] = saWo[((size_t)l*HS + f0+ff)*HS + e0 + k]; }
      { int jj = idx & 63, k = idx >> 6;
        Bs[k][jj] = saWin[((size_t)l*(3*HS) + 2*HS + e0 + k)*HS + j0 + jj]; }
    }
    __syncthreads();
#pragma unroll
    for (int k = 0; k < 16; ++k) {
      float a[4], b[4];
#pragma unroll
      for (int xx = 0; xx < 4; ++xx) { a[xx] = As[k][tm*4+xx]; b[xx] = Bs[k][tf*4+xx]; }
#pragma unroll
      for (int xx = 0; xx < 4; ++xx)
#pragma unroll
        for (int y = 0; y < 4; ++y) acc[xx][y] += a[xx]*b[y];
    }
    __syncthreads();
  }
#pragma unroll
  for (int xx = 0; xx < 4; ++xx)
#pragma unroll
    for (int y = 0; y < 4; ++y)
      wcomb[(size_t)l*HS*HS + (size_t)(f0+tm*4+xx)*HS + (j0+tf*4+y)] = f2bf(acc[xx][y]);
}

__global__ __launch_bounds__(256) void pack_wq(
    const float* __restrict__ caWin, const float* __restrict__ lnG,
    ushortt* __restrict__ wqp) {
  const int b = blockIdx.x, l = blockIdx.y;
  for (int idx = threadIdx.x; idx < 512*16; idx += 256) {
    int f = idx >> 4, r = idx & 15, j = b*16 + r;
    wqp[(((size_t)l*32 + b)*512 + f)*16 + r] =
        f2bf(caWin[((size_t)l*3*HS + f)*HS + j] * lnG[l*3*HS + j]);
  }
}

__global__ __launch_bounds__(256) void pack_w2(
    const float* __restrict__ ffW2, ushortt* __restrict__ w2p) {
  const int bid = blockIdx.x, l = blockIdx.y;
  for (int idx = threadIdx.x; idx < 512*8; idx += 256) {
    int f = idx >> 3, r = idx & 7;
    w2p[(((size_t)l*NB + bid)*512 + f)*8 + r] =
        f2bf(ffW2[((size_t)l*HS + f)*FFD + bid*8 + r]);
  }
}

__global__ __launch_bounds__(256) void bf16_copy(
    const float* __restrict__ in, ushortt* __restrict__ out, size_t n) {
  for (size_t i = (size_t)blockIdx.x*256 + threadIdx.x; i < n; i += (size_t)gridDim.x*256)
    out[i] = f2bf(in[i]);
}

__global__ __launch_bounds__(256) void csa_kernel(
    const float* __restrict__ saWo, const float* __restrict__ sabin,
    const float* __restrict__ sabo, float* __restrict__ csa) {
  const int w = threadIdx.x >> 6, lane = threadIdx.x & 63;
  const int row = blockIdx.x*4 + w;
  const int l = row >> 9, f = row & 511;
  float acc = 0;
#pragma unroll
  for (int k = 0; k < 8; ++k) {
    int e = lane + 64*k;
    acc += saWo[((size_t)l*HS + f)*HS + e] * sabin[l*(3*HS) + 2*HS + e];
  }
  acc = wred(acc);
  if (lane == 0) csa[row] = acc + sabo[l*HS + f];
}

__global__ __launch_bounds__(256) void sqcbq_kernel(
    const float* __restrict__ caWin, const float* __restrict__ caBin,
    const float* __restrict__ lnG, const float* __restrict__ lnB,
    float* __restrict__ sq, float* __restrict__ cbq) {
  const int w = threadIdx.x >> 6, lane = threadIdx.x & 63;
  const int row = blockIdx.x*4 + w;
  const int l = row >> 9, f = row & 511;
  float a1 = 0, a2 = 0;
#pragma unroll
  for (int k = 0; k < 8; ++k) {
    int e = lane + 64*k;
    float wv = caWin[((size_t)l*(3*HS) + f)*HS + e];
    a1 += wv * lnG[l*(3*HS) + e];
    a2 += wv * lnB[l*(3*HS) + e];
  }
  a1 = wred(a1); a2 = wred(a2);
  if (lane == 0) { sq[row] = a1; cbq[row] = a2 + caBin[l*(3*HS) + f]; }
}

// ---------------- main persistent sequential kernel ----------------
// winA: update+z1 (0-63) | z0/z2 via xing-join (64-191) | J1 -> H2 (0-31)
// bar1 | winB: attn owner-ctx (32-159) | J2 -> H4 (0-31) | Y2p zero (160-223)
// bar2 | H5 all (Y2p 4-way) | bar3
// FIX vs R13: xing flag published UNCONDITIONALLY (was skipped at i==3 -> deadlock)

__global__ __launch_bounds__(NT, 1) void seq_kernel(
    const float* __restrict__ x,
    const float* __restrict__ bx, const float* __restrict__ bh,
    const float* __restrict__ caBo,
    const float* __restrict__ ffB1,
    const float* __restrict__ ffB2,
    const float* __restrict__ lnG,  const float* __restrict__ lnB,
    float* __restrict__ ws, float* __restrict__ out) {
  const ushortt* Kb    = (const ushortt*)(ws + OFF_KBF);
  const ushortt* Vt    = (const ushortt*)(ws + OFF_VBF);
  const ushortt* Wcomb = (const ushortt*)(ws + OFF_WCOMBBF);
  const ushortt* WQP   = (const ushortt*)(ws + OFF_WQP);
  const ushortt* W2P   = (const ushortt*)(ws + OFF_W2P);
  const ushortt* F1b   = (const ushortt*)(ws + OFF_FFW1BF);
  const ushortt* CaWob = (const ushortt*)(ws + OFF_CAWOBF);
  const ushortt* WXb   = (const ushortt*)(ws + OFF_WXBF);
  const ushortt* WHb   = (const ushortt*)(ws + OFF_WHBF);
  const float* csag  = ws + OFF_CSA;
  const float* sqg   = ws + OFF_SQ;
  const float* cbqg  = ws + OFF_CBQ;
  float* hG    = ws + OFF_H;
  float* cG    = ws + OFF_C;
  float* xing  = ws + OFF_XING;
  float* z1g   = ws + OFF_Z1;
  float* z02g  = ws + OFF_Z02;
  float* t2g   = ws + OFF_T2G;
  float* Yp    = ws + OFF_YP;
  float* Y2p   = ws + OFF_Y2P;
  float* ctxP  = ws + OFF_CTXP;
  float* denS  = ws + OFF_DENS;
  float* s1s   = ws + OFF_S1S;
  float* s2s   = ws + OFF_S2S;
  unsigned* J1     = (unsigned*)(ws + OFF_J1);
  unsigned* J2     = (unsigned*)(ws + OFF_J2);
  unsigned* xfl    = (unsigned*)(ws + OFF_XFL);
  unsigned* bflags = (unsigned*)(ws + OFF_FLAGS);

  __shared__ float sh_xin[HS], sh_h[HS], sh_vec[HS], sh_aux[HS];
  __shared__ float sh_q[128], sh_p[64], sh_t1[16];
  __shared__ float sh_red[24], sh_den[4];

  const int bid = blockIdx.x, tid = threadIdx.x;
  const int w = tid >> 6, lane = tid & 63;
  const int g4 = tid >> 7, dd = tid & 127;
  unsigned gen = 1;

  unsigned pZx[4],  pZh[4];       // z1 rows (bid<64)
  unsigned pZx2[4], pZh2[4];      // z0/z2 rows (64<=bid<192)
  unsigned pWc[2][4], pWq[8];     // H2 (bid<32)
  unsigned pK[2][4],  pV[8];      // attn (32<=bid<160)
  unsigned pCa[2][4];             // H4 (bid<32)
  unsigned pF1[4], pW2[4];        // H5 (all)

  auto pfH1 = [&](int l) {
    if (bid < 64) {
      const size_t ro = (((size_t)l*3 + 1)*HS + bid*8 + w)*HS + lane*8;
      ld8bfp(WXb + ro, pZx);
      ld8bfp(WHb + ro, pZh);
    }
  };
  auto pfZ02 = [&](int l) {
    if (bid >= 64 && bid < 192) {
      const int zb = bid - 64, rowid = zb*8 + w;
      const int g = (rowid < 512) ? 0 : 2, f = rowid & 511;
      const size_t ro = (((size_t)l*3 + g)*HS + f)*HS + lane*8;
      ld8bfp(WXb + ro, pZx2);
      ld8bfp(WHb + ro, pZh2);
    }
  };
  auto pfH2 = [&](int l) {
    if (bid < 32) {
#pragma unroll
      for (int rr = 0; rr < 2; ++rr)
        ld8bfp(Wcomb + ((size_t)l*HS + bid*16 + w*2 + rr)*HS + lane*8, pWc[rr]);
      const ushortt* q = WQP + (((size_t)l*32 + bid)*512 + tid)*16;
      ld8bfp(q,     pWq);
      ld8bfp(q + 8, pWq + 4);
    }
  };
  auto pfH3 = [&](int l) {
    if (bid >= 32 && bid < 160) {
      const int b2 = bid - 32, h = b2 >> 5, ms = b2 & 31;
#pragma unroll
      for (int rr = 0; rr < 2; ++rr)
        ld8bfp(Kb + ((size_t)l*MMEM + ms*64 + w*8 + (lane>>4) + 4*rr)*HS
                  + h*128 + (lane & 15)*8, pK[rr]);
      const ushortt* vp = Vt + (size_t)l*MMEM*HS
                        + ((size_t)h*128 + dd)*MMEM + ms*64 + g4*16;
      ld8bfp(vp,     pV);
      ld8bfp(vp + 8, pV + 4);
    }
  };
  auto pfH4 = [&](int l) {
    if (bid < 32) {
#pragma unroll
      for (int rr = 0; rr < 2; ++rr)
        ld8bfp(CaWob + ((size_t)l*HS + bid*16 + w*2 + rr)*HS + lane*8, pCa[rr]);
    }
  };
  auto pfH5 = [&](int l) {
    ld8bfp(F1b + ((size_t)l*FFD + bid*8 + w)*HS + lane*8, pF1);
    ld8bfp(W2P + (((size_t)l*NB + bid)*512 + tid)*8, pW2);
  };

  auto do_update = [&](int ip, int parp, int pz, float& xn, float& cn) {
    const int j = tid;
    float t2v = ald(t2g + j);
    float z0  = ald(z02g + pz*1024 + j);
    float z2  = ald(z02g + pz*1024 + HS + j);
    float y2 = 0;
    {
      float yv[16];
#pragma unroll
      for (int c = 0; c < 64; c += 16) {
#pragma unroll
        for (int p = 0; p < 16; ++p) yv[p] = ald(Y2p + (size_t)(c+p)*HS + j);
#pragma unroll
        for (int p = 0; p < 16; ++p) y2 += yv[p];
      }
    }
    slotred32(s2s, sh_red, 16, w, lane);
    __syncthreads();
    float m2 = sh_red[16]*INV512;
    float r2 = rsqrtf(sh_red[17]*INV512 - m2*m2 + 1e-5f);
    float x2 = (t2v-m2)*r2*lnG[(ip*3+1)*HS+j] + lnB[(ip*3+1)*HS+j];
    float t3 = x2 + y2 + ffB2[ip*HS + j];
    float s_ = t3, q_ = t3*t3;
#pragma unroll
    for (int m = 32; m; m >>= 1) { s_ += __shfl_xor(s_, m); q_ += __shfl_xor(q_, m); }
    if (lane == 0) { sh_red[w] = s_; sh_red[8+w] = q_; }
    __syncthreads();
    if (tid == 0) {
      float a = 0, b = 0;
#pragma unroll
      for (int k = 0; k < 8; ++k) { a += sh_red[k]; b += sh_red[8+k]; }
      sh_red[0] = a; sh_red[1] = b;
    }
    __syncthreads();
    float m3 = sh_red[0]*INV512;
    float r3 = rsqrtf(sh_red[1]*INV512 - m3*m3 + 1e-5f);
    float d  = (t3-m3)*r3*lnG[(ip*3+2)*HS+j] + lnB[(ip*3+2)*HS+j];
    float cp = ald(cG + (parp*LNUM + ip)*HS + j);
    float ft = sigm(cp - d);
    float it = sigm(z0);
    float gt = tanhf(z2);
    cn = ft*cp + it*gt;
    xn = tanhf(cn);
  };

  pfH1(0); pfZ02(0); pfH2(0); pfH3(0);

  for (int s = 0; s < TT*LNUM; ++s) {
    const int t = s >> 2, i = s & 3;
    const int par = t & 1;
    const int pz = s & 1;
    const unsigned jv = (unsigned)(s + 1);
    // ---------- winA ----------
    if (bid < 64) {
      float xn = 0.f, cn = 0.f;
      if (s > 0) {
        const int ip = (s-1) & 3, tp = (s-1) >> 2, parp = tp & 1;
        if (bid == 0 || i > 0) {
          do_update(ip, parp, (s-1) & 1, xn, cn);
          if (bid == 0) {
            ast(hG + ((parp^1)*LNUM + ip)*HS + tid, xn);
            ast(cG + ((parp^1)*LNUM + ip)*HS + tid, cn);
            if (ip == 3) out[tp*HS + tid] = xn;
          }
        }
      }
      float xv = (i == 0) ? x[t*HS + tid] : xn;
      sh_xin[tid] = xv;
      sh_h[tid]   = ald(hG + (par*LNUM + i)*HS + tid);
      if (bid == 0) ast(xing + tid, xv);
      __syncthreads();
      if (bid == 0) {    // ALWAYS publish xing flag (R13 deadlock fix)
        asm volatile("s_waitcnt vmcnt(0)" ::: "memory");
        __syncthreads();
        if (tid < 4) astu(xfl + (size_t)tid*32, jv);
      }
      const int f = bid*8 + w;
      float acc = 0;
#pragma unroll
      for (int k = 0; k < 4; ++k) {
        unsigned px = pZx[k], ph = pZh[k];
        acc += bflo(px)*sh_xin[lane*8 + 2*k] + bfhi(px)*sh_xin[lane*8 + 2*k + 1]
             + bflo(ph)*sh_h[lane*8 + 2*k]  + bfhi(ph)*sh_h[lane*8 + 2*k + 1];
      }
      acc = wred(acc);
      if (lane == 0) ast(z1g + f, acc + bx[(i*3+1)*HS + f] + bh[(i*3+1)*HS + f]);
      jflag(J1, bid, jv);
    } else if (bid < 192) {
      const int zb = bid - 64;
      float xv;
      if (i == 0) xv = x[t*HS + tid];
      else {
        if (tid == 0) {
          const unsigned* f = xfl + (size_t)(bid & 3)*32;
          while ((int)(aldu(f) - jv) < 0) __builtin_amdgcn_s_sleep(1);
        }
        __syncthreads();
        xv = ald(xing + tid);
      }
      sh_xin[tid] = xv;
      sh_h[tid]   = ald(hG + (par*LNUM + i)*HS + tid);
      __syncthreads();
      const int rowid = zb*8 + w;
      const int g = (rowid < 512) ? 0 : 2, f = rowid & 511;
      float acc = 0;
#pragma unroll
      for (int k = 0; k < 4; ++k) {
        unsigned px = pZx2[k], ph = pZh2[k];
        acc += bflo(px)*sh_xin[lane*8 + 2*k] + bfhi(px)*sh_xin[lane*8 + 2*k + 1]
             + bflo(ph)*sh_h[lane*8 + 2*k]  + bfhi(ph)*sh_h[lane*8 + 2*k + 1];
      }
      acc = wred(acc);
      if (lane == 0)
        ast(z02g + pz*1024 + (g ? HS : 0) + f,
            acc + bx[(i*3+g)*HS + f] + bh[(i*3+g)*HS + f]);
    }
    // ---------- J1 -> H2 (0-31): t1 + Y owner plane + s1 slots ----------
    if (bid < 32) {
      jwait(J1, 64, jv);
      sh_vec[tid] = sigm(ald(z1g + tid));  // f0
      __syncthreads();
#pragma unroll
      for (int rr = 0; rr < 2; ++rr) {
        const int r = w*2 + rr, j = bid*16 + r;
        float acc = 0;
#pragma unroll
        for (int k = 0; k < 4; ++k) {
          unsigned pw = pWc[rr][k];
          acc += bflo(pw)*sh_vec[lane*8 + 2*k] + bfhi(pw)*sh_vec[lane*8 + 2*k + 1];
        }
        acc = wred(acc);
        if (lane == 0) {
          float t1v = sh_vec[j] + acc + csag[i*HS + j];
          sh_t1[r]  = t1v;
          sh_aux[r] = t1v;
        }
      }
      __syncthreads();
      {
        float yl = 0;
#pragma unroll
        for (int q = 0; q < 8; ++q) {
          unsigned pw = pWq[q];
          yl += sh_aux[2*q]*bflo(pw) + sh_aux[2*q+1]*bfhi(pw);
        }
        ast(Yp + (size_t)bid*HS + tid, yl);   // owner plane
      }
      if (w == 0 && lane < 16) {
        float v = sh_aux[lane], s_ = v, q_ = v*v;
#pragma unroll
        for (int m = 8; m; m >>= 1) { s_ += __shfl_xor(s_, m); q_ += __shfl_xor(q_, m); }
        if (lane == 0) { ast(s1s + bid*2, s_); ast(s1s + bid*2 + 1, q_); }
      }
    }
    barrier_pf(bflags, gen, [&]{ pfH4(i); pfH5(i); });
    // ---------- winB ----------
    if (bid >= 32 && bid < 160) {
      const int b2 = bid - 32, h = b2 >> 5;
      slotred32(s1s, sh_red, 18, w, lane);
      {   // Y sum: 8 owner planes per thread-group (32 total)
        float part = 0;
        float yv[8];
#pragma unroll
        for (int p = 0; p < 8; ++p) yv[p] = ald(Yp + (size_t)(g4*8+p)*HS + h*128 + dd);
#pragma unroll
        for (int p = 0; p < 8; ++p) part += yv[p];
        sh_vec[tid] = part;
      }
      __syncthreads();
      if (tid < 128) {
        float Ysum = sh_vec[tid] + sh_vec[128+tid] + sh_vec[256+tid] + sh_vec[384+tid];
        float m1 = sh_red[18]*INV512;
        float r1 = rsqrtf(sh_red[19]*INV512 - m1*m1 + 1e-5f);
        int f = h*128 + tid;
        sh_q[tid] = r1*(Ysum - m1*sqg[i*HS + f]) + cbqg[i*HS + f];
      }
      __syncthreads();
#pragma unroll
      for (int rr = 0; rr < 2; ++rr) {
        float sc = 0;
#pragma unroll
        for (int k = 0; k < 4; ++k) {
          unsigned pw = pK[rr][k];
          sc += bflo(pw)*sh_q[(lane & 15)*8 + 2*k] + bfhi(pw)*sh_q[(lane & 15)*8 + 2*k + 1];
        }
#pragma unroll
        for (int msk = 8; msk; msk >>= 1) sc += __shfl_xor(sc, msk);
        if ((lane & 15) == 0) sh_p[w*8 + (lane >> 4) + 4*rr] = __expf(sc * QSCALE);
      }
      __syncthreads();
      {   // ctx: in-LDS 4-group reduce then owner-plane write
        float acc = 0;
#pragma unroll
        for (int q = 0; q < 8; ++q) {
          unsigned pw = pV[q];
          acc += sh_p[g4*16 + 2*q]*bflo(pw) + sh_p[g4*16 + 2*q + 1]*bfhi(pw);
        }
        sh_vec[tid] = acc;
      }
      if (w == 0) {
        float v = wred(sh_p[lane]);
        if (lane == 0) ast(denS + b2, v);
      }
      __syncthreads();
      if (tid < 128) {
        float tot = sh_vec[tid] + sh_vec[128+tid] + sh_vec[256+tid] + sh_vec[384+tid];
        ast(ctxP + (size_t)b2*128 + tid, tot);
      }
      jflag(J2, b2, jv);
    } else if (bid < 32) {
      jwait(J2, 128, jv);
      slotred32(s1s, sh_red, 18, w, lane);
      if (w >= 4) {
        float v = (lane < 32) ? ald(denS + (w-4)*32 + lane) : 0.f;
#pragma unroll
        for (int m = 16; m; m >>= 1) v += __shfl_xor(v, m);
        if (lane == 0) sh_den[w-4] = v;
      }
      __syncthreads();
      const float m1 = sh_red[18]*INV512;
      const float r1 = rsqrtf(sh_red[19]*INV512 - m1*m1 + 1e-5f);
      {   // ctx sum: 32 owner planes for this thread's head
        const int hh = tid >> 7;
        float c0 = 0;
        float cv[16];
#pragma unroll
        for (int c = 0; c < 32; c += 16) {
#pragma unroll
          for (int p = 0; p < 16; ++p)
            cv[p] = ald(ctxP + (size_t)(hh*32 + c + p)*128 + dd);
#pragma unroll
          for (int p = 0; p < 16; ++p) c0 += cv[p];
        }
        sh_vec[tid] = c0 / sh_den[hh];
      }
      __syncthreads();
#pragma unroll
      for (int rr = 0; rr < 2; ++rr) {
        const int r = w*2 + rr, j = bid*16 + r;
        float a2 = 0;
#pragma unroll
        for (int k = 0; k < 4; ++k) {
          unsigned pw = pCa[rr][k];
          a2 += bflo(pw)*sh_vec[lane*8 + 2*k] + bfhi(pw)*sh_vec[lane*8 + 2*k + 1];
        }
        a2 = wred(a2);
        if (lane == 0) {
          float x1 = (sh_t1[r]-m1)*r1*lnG[(i*3)*HS + j] + lnB[(i*3)*HS + j];
          float t2v = x1 + a2 + caBo[i*HS + j];
          ast(t2g + j, t2v);
          sh_aux[r] = t2v;
        }
      }
      __syncthreads();
      if (w == 0 && lane < 16) {
        float v = sh_aux[lane], s_ = v, q_ = v*v;
#pragma unroll
        for (int m = 8; m; m >>= 1) { s_ += __shfl_xor(s_, m); q_ += __shfl_xor(q_, m); }
        if (lane == 0) { ast(s2s + bid*2, s_); ast(s2s + bid*2 + 1, q_); }
      }
    } else if (bid >= 160 && bid < 224) {
      ast(Y2p + (size_t)(bid-160)*HS + tid, 0.f);   // zero for H5's 4-way adds
    }
    barrier_pf(bflags, gen+1, [&]{ const int nl = (s+1) & 3; pfH1(nl); pfZ02(nl); });
    // ---------- H5: all blocks ----------
    {
      slotred32(s2s, sh_red, 16, w, lane);
      __syncthreads();
      const float m2 = sh_red[16]*INV512;
      const float r2 = rsqrtf(sh_red[17]*INV512 - m2*m2 + 1e-5f);
      sh_vec[tid] = (ald(t2g + tid)-m2)*r2*lnG[(i*3+1)*HS + tid] + lnB[(i*3+1)*HS + tid];
      __syncthreads();
      const int kk = bid*8 + w;
      float acc = 0;
#pragma unroll
      for (int k = 0; k < 4; ++k) {
        unsigned pw = pF1[k];
        acc += bflo(pw)*sh_vec[lane*8 + 2*k] + bfhi(pw)*sh_vec[lane*8 + 2*k + 1];
      }
      acc = wred(acc);
      if (lane == 0) sh_aux[w] = fmaxf(acc + ffB1[i*FFD + kk], 0.f);
      __syncthreads();
      float yl = 0;
#pragma unroll
      for (int q = 0; q < 4; ++q) {
        unsigned pw = pW2[q];
        yl += sh_aux[2*q]*bflo(pw) + sh_aux[2*q+1]*bfhi(pw);
      }
      atomicAdd(&Y2p[(size_t)(bid & 63)*HS + tid], yl);   // 4-way only
    }
    barrier_pf(bflags, gen+2, [&]{ const int nl = (s+1) & 3; pfH2(nl); pfH3(nl); });
    gen += 3;
  }

  // ---------- epilogue ----------
  if (bid == 0) {
    float xn, cn;
    do_update(3, 1, 1, xn, cn);
    out[127*HS + tid] = xn;
    out[TT*HS + 3*HS + tid] = xn;
    out[TT*HS + LNUM*HS + 3*HS + tid] = cn;
#pragma unroll
    for (int ii = 0; ii < 3; ++ii) {
      out[TT*HS + ii*HS + tid]            = ald(hG + (0*LNUM + ii)*HS + tid);
      out[TT*HS + LNUM*HS + ii*HS + tid]  = ald(cG + (0*LNUM + ii)*HS + tid);
    }
  }
}

// ---------------- host launcher ----------------
extern "C" void kernel_launch(void* const* d_in, const int* in_sizes, int n_in,
                              void* d_out, int out_size, void* d_ws, size_t ws_size,
                              hipStream_t stream) {
  const float* x      = (const float*)d_in[0];
  const float* hist   = (const float*)d_in[1];
  const float* Wx     = (const float*)d_in[2];
  const float* bx     = (const float*)d_in[3];
  const float* Wh     = (const float*)d_in[4];
  const float* bh     = (const float*)d_in[5];
  const float* saWin  = (const float*)d_in[6];
  const float* saBin  = (const float*)d_in[7];
  const float* saWo   = (const float*)d_in[8];
  const float* saBo   = (const float*)d_in[9];
  const float* caWin  = (const float*)d_in[10];
  const float* caBin  = (const float*)d_in[11];
  const float* caWo   = (const float*)d_in[12];
  const float* caBo   = (const float*)d_in[13];
  const float* ffW1   = (const float*)d_in[14];
  const float* ffB1   = (const float*)d_in[15];
  const float* ffW2   = (const float*)d_in[16];
  const float* ffB2   = (const float*)d_in[17];
  const float* lnG    = (const float*)d_in[18];
  const float* lnB    = (const float*)d_in[19];
  float* ws  = (float*)d_ws;
  float* out = (float*)d_out;

  hipMemsetAsync((char*)d_ws + OFF_STATE*sizeof(float), 0,
                 (WS_TOTAL - OFF_STATE)*sizeof(float), stream);

  kv_gemm<<<dim3(MMEM/64, HS/64, LNUM), 256, 0, stream>>>(
      hist, caWin, caBin, (ushortt*)(ws + OFF_KBF), HS, 0);
  kv_gemm<<<dim3(MMEM/64, HS/64, LNUM), 256, 0, stream>>>(
      hist, caWin, caBin, (ushortt*)(ws + OFF_VBF), 2*HS, 1);
  wcomb_gemm<<<dim3(HS/64, HS/64, LNUM), 256, 0, stream>>>(
      saWo, saWin, (ushortt*)(ws + OFF_WCOMBBF));
  csa_kernel<<<(LNUM*HS)/4, 256, 0, stream>>>(saWo, saBin, saBo, ws + OFF_CSA);
  pack_wq<<<dim3(32, LNUM), 256, 0, stream>>>(caWin, lnG, (ushortt*)(ws + OFF_WQP));
  sqcbq_kernel<<<(LNUM*HS)/4, 256, 0, stream>>>(caWin, caBin, lnG, lnB, ws + OFF_SQ, ws + OFF_CBQ);
  pack_w2<<<dim3(NB, LNUM), 256, 0, stream>>>(ffW2, (ushortt*)(ws + OFF_W2P));
  bf16_copy<<<2048, 256, 0, stream>>>(ffW1, (ushortt*)(ws + OFF_FFW1BF), (size_t)LNUM*FFD*HS);
  bf16_copy<<<1024, 256, 0, stream>>>(caWo, (ushortt*)(ws + OFF_CAWOBF), (size_t)LNUM*HS*HS);
  bf16_copy<<<2048, 256, 0, stream>>>(Wx, (ushortt*)(ws + OFF_WXBF), (size_t)LNUM*3*HS*HS);
  bf16_copy<<<2048, 256, 0, stream>>>(Wh, (ushortt*)(ws + OFF_WHBF), (size_t)LNUM*3*HS*HS);

  seq_kernel<<<NB, NT, 0, stream>>>(x, bx, bh, caBo,
                                    ffB1, ffB2, lnG, lnB, ws, out);
}

// Round 15
// 11099.162 us; speedup vs baseline: 1.9491x; 1.9491x over previous
//
#include <hip/hip_runtime.h>

#define HS   512
#define LNUM 4
#define TT   128
#define MMEM 2048
#define FFD  2048
#define NB   256
#define NT   512
#define INV512 (1.0f/512.0f)
#define QSCALE 0.08838834764831845f  // 1/sqrt(128)

typedef unsigned short ushortt;

// ---------------- workspace layout (float offsets) ----------------
constexpr size_t KHALF = (size_t)LNUM*MMEM*HS/2;
constexpr size_t HHALF = (size_t)LNUM*HS*HS/2;
constexpr size_t FHALF = (size_t)LNUM*FFD*HS/2;
constexpr size_t GHALF = (size_t)LNUM*3*HS*HS/2;
constexpr size_t OFF_KBF    = 0;
constexpr size_t OFF_VBF    = OFF_KBF    + KHALF;   // V transposed [l][f][m]
constexpr size_t OFF_WCOMBBF= OFF_VBF    + KHALF;
constexpr size_t OFF_WQP    = OFF_WCOMBBF+ HHALF;   // packed [l][b][f][16]
constexpr size_t OFF_W2P    = OFF_WQP    + HHALF;   // packed [l][bid][f][8]
constexpr size_t OFF_FFW1BF = OFF_W2P    + FHALF;
constexpr size_t OFF_CAWOBF = OFF_FFW1BF + FHALF;
constexpr size_t OFF_WXBF   = OFF_CAWOBF + HHALF;   // bf16 Wx
constexpr size_t OFF_WHBF   = OFF_WXBF   + GHALF;   // bf16 Wh
constexpr size_t OFF_CSA    = OFF_WHBF   + GHALF;
constexpr size_t OFF_SQ     = OFF_CSA    + (size_t)LNUM*HS;
constexpr size_t OFF_CBQ    = OFF_SQ     + (size_t)LNUM*HS;
// mutable (memset 0)
constexpr size_t OFF_STATE = OFF_CBQ   + (size_t)LNUM*HS;
constexpr size_t OFF_H     = OFF_STATE;                           // [2][4][512]
constexpr size_t OFF_C     = OFF_H     + 2*LNUM*HS;
constexpr size_t OFF_XING  = OFF_C     + 2*LNUM*HS;               // 512
constexpr size_t OFF_Z1    = OFF_XING  + HS;                      // 512
constexpr size_t OFF_Z02   = OFF_Z1    + HS;                      // 1024
constexpr size_t OFF_T2G   = OFF_Z02   + 2*HS;                    // 512
constexpr size_t OFF_YP    = OFF_T2G   + HS;                      // 4*HS planes
constexpr size_t OFF_Y2P   = OFF_YP    + 4*HS;                    // 8*HS planes
constexpr size_t OFF_CTXP  = OFF_Y2P   + 8*HS;                    // 8*HS planes
constexpr size_t OFF_DENS  = OFF_CTXP  + 8*HS;                    // 128 slots
constexpr size_t OFF_S1S   = OFF_DENS  + 128;                     // 32*2 slots
constexpr size_t OFF_S2S   = OFF_S1S   + 64;                      // 32*2 slots
constexpr size_t OFF_J1    = OFF_S2S   + 64;                      // 65*32 u32
constexpr size_t OFF_J2    = OFF_J1    + 65*32;                   // 128*32 u32
constexpr size_t OFF_FLAGS = OFF_J2    + 128*32;                  // NB*32 u32
constexpr size_t WS_TOTAL  = OFF_FLAGS + (size_t)NB*32;

__device__ __forceinline__ float wred(float v) {
#pragma unroll
  for (int m = 32; m; m >>= 1) v += __shfl_xor(v, m);
  return v;
}
__device__ __forceinline__ float sigm(float x) { return 1.0f/(1.0f+__expf(-x)); }
__device__ __forceinline__ ushortt f2bf(float f) {
  unsigned u = __float_as_uint(f);
  return (ushortt)((u + 0x7fffu + ((u >> 16) & 1u)) >> 16);
}
__device__ __forceinline__ float bflo(unsigned v){ return __uint_as_float(v << 16); }
__device__ __forceinline__ float bfhi(unsigned v){ return __uint_as_float(v & 0xffff0000u); }
__device__ __forceinline__ void ld8bfp(const ushortt* p, unsigned* d) {
  uint4 v = *(const uint4*)p;
  d[0] = v.x; d[1] = v.y; d[2] = v.z; d[3] = v.w;
}

__device__ __forceinline__ float ald(const float* p) {
  return __hip_atomic_load(p, __ATOMIC_RELAXED, __HIP_MEMORY_SCOPE_AGENT);
}
__device__ __forceinline__ void ast(float* p, float v) {
  __hip_atomic_store(p, v, __ATOMIC_RELAXED, __HIP_MEMORY_SCOPE_AGENT);
}
__device__ __forceinline__ unsigned aldu(const unsigned* p) {
  return __hip_atomic_load(p, __ATOMIC_RELAXED, __HIP_MEMORY_SCOPE_AGENT);
}
__device__ __forceinline__ void astu(unsigned* p, unsigned v) {
  __hip_atomic_store(p, v, __ATOMIC_RELAXED, __HIP_MEMORY_SCOPE_AGENT);
}

template <class F>
__device__ __forceinline__ void barrier_pf(unsigned* flags, unsigned g, F&& pf) {
  asm volatile("s_waitcnt vmcnt(0)" ::: "memory");
  __syncthreads();
  if (threadIdx.x == 0) astu(flags + (size_t)blockIdx.x*32, g);
  pf();
  if (threadIdx.x < NB) {
    const unsigned* f = flags + (size_t)threadIdx.x*32;
    while ((int)(aldu(f) - g) < 0) __builtin_amdgcn_s_sleep(2);
  }
  __syncthreads();
}
__device__ __forceinline__ void jflag(unsigned* J, int id, unsigned val) {
  asm volatile("s_waitcnt vmcnt(0)" ::: "memory");
  __syncthreads();
  if (threadIdx.x == 0) astu(J + (size_t)id*32, val);
}
template <class F>
__device__ __forceinline__ void jwait_pf(unsigned* J, int n, unsigned val, F&& pf) {
  pf();
  if (threadIdx.x < n) {
    const unsigned* f = J + (size_t)threadIdx.x*32;
    while ((int)(aldu(f) - val) < 0) __builtin_amdgcn_s_sleep(1);
  }
  __syncthreads();
}
__device__ __forceinline__ void slotred32(const float* slots, float* sh, int o,
                                          int w, int lane) {
  if (w == 0) {
    float a = (lane < 32) ? ald(slots + lane*2) : ald(slots + (lane-32)*2 + 1);
#pragma unroll
    for (int m = 16; m; m >>= 1) a += __shfl_xor(a, m);
    if (lane == 0)  sh[o]   = a;
    if (lane == 32) sh[o+1] = a;
  }
}

// ---------------- precompute kernels ----------------

__global__ __launch_bounds__(256) void kv_gemm(
    const float* __restrict__ hist, const float* __restrict__ caWin,
    const float* __restrict__ caBin, ushortt* __restrict__ out, int koff, int vt) {
  __shared__ float As[16][64];
  __shared__ float Bs[16][64];
  const int l = blockIdx.z, m0 = blockIdx.x*64, f0 = blockIdx.y*64;
  const int tid = threadIdx.x, tm = tid >> 4, tf = tid & 15;
  float acc[4][4] = {};
  for (int e0 = 0; e0 < HS; e0 += 16) {
#pragma unroll
    for (int it = 0; it < 4; ++it) {
      int idx = tid + it*256, k = idx & 15, mm = idx >> 4;
      As[k][mm] = hist[((size_t)(m0+mm)*LNUM + l)*HS + e0 + k];
      Bs[k][mm] = caWin[((size_t)l*(3*HS) + koff + f0 + mm)*HS + e0 + k];
    }
    __syncthreads();
#pragma unroll
    for (int k = 0; k < 16; ++k) {
      float a[4], b[4];
#pragma unroll
      for (int xx = 0; xx < 4; ++xx) { a[xx] = As[k][tm*4+xx]; b[xx] = Bs[k][tf*4+xx]; }
#pragma unroll
      for (int xx = 0; xx < 4; ++xx)
#pragma unroll
        for (int y = 0; y < 4; ++y) acc[xx][y] += a[xx]*b[y];
    }
    __syncthreads();
  }
#pragma unroll
  for (int xx = 0; xx < 4; ++xx)
#pragma unroll
    for (int y = 0; y < 4; ++y) {
      int m = m0 + tm*4 + xx, f = f0 + tf*4 + y;
      ushortt v = f2bf(acc[xx][y] + caBin[l*(3*HS) + koff + f]);
      if (vt) out[(size_t)l*MMEM*HS + (size_t)f*MMEM + m] = v;
      else    out[((size_t)l*MMEM + m)*HS + f] = v;
    }
}

__global__ __launch_bounds__(256) void wcomb_gemm(
    const float* __restrict__ saWo, const float* __restrict__ saWin,
    ushortt* __restrict__ wcomb) {
  __shared__ float As[16][64];
  __shared__ float Bs[16][64];
  const int l = blockIdx.z, f0 = blockIdx.x*64, j0 = blockIdx.y*64;
  const int tid = threadIdx.x, tm = tid >> 4, tf = tid & 15;
  float acc[4][4] = {};
  for (int e0 = 0; e0 < HS; e0 += 16) {
#pragma unroll
    for (int it = 0; it < 4; ++it) {
      int idx = tid + it*256;
      { int k = idx & 15, ff = idx >> 4;
        As[k][ff] = saWo[((size_t)l*HS + f0+ff)*HS + e0 + k]; }
      { int jj = idx & 63, k = idx >> 6;
        Bs[k][jj] = saWin[((size_t)l*(3*HS) + 2*HS + e0 + k)*HS + j0 + jj]; }
    }
    __syncthreads();
#pragma unroll
    for (int k = 0; k < 16; ++k) {
      float a[4], b[4];
#pragma unroll
      for (int xx = 0; xx < 4; ++xx) { a[xx] = As[k][tm*4+xx]; b[xx] = Bs[k][tf*4+xx]; }
#pragma unroll
      for (int xx = 0; xx < 4; ++xx)
#pragma unroll
        for (int y = 0; y < 4; ++y) acc[xx][y] += a[xx]*b[y];
    }
    __syncthreads();
  }
#pragma unroll
  for (int xx = 0; xx < 4; ++xx)
#pragma unroll
    for (int y = 0; y < 4; ++y)
      wcomb[(size_t)l*HS*HS + (size_t)(f0+tm*4+xx)*HS + (j0+tf*4+y)] = f2bf(acc[xx][y]);
}

__global__ __launch_bounds__(256) void pack_wq(
    const float* __restrict__ caWin, const float* __restrict__ lnG,
    ushortt* __restrict__ wqp) {
  const int b = blockIdx.x, l = blockIdx.y;
  for (int idx = threadIdx.x; idx < 512*16; idx += 256) {
    int f = idx >> 4, r = idx & 15, j = b*16 + r;
    wqp[(((size_t)l*32 + b)*512 + f)*16 + r] =
        f2bf(caWin[((size_t)l*3*HS + f)*HS + j] * lnG[l*3*HS + j]);
  }
}

__global__ __launch_bounds__(256) void pack_w2(
    const float* __restrict__ ffW2, ushortt* __restrict__ w2p) {
  const int bid = blockIdx.x, l = blockIdx.y;
  for (int idx = threadIdx.x; idx < 512*8; idx += 256) {
    int f = idx >> 3, r = idx & 7;
    w2p[(((size_t)l*NB + bid)*512 + f)*8 + r] =
        f2bf(ffW2[((size_t)l*HS + f)*FFD + bid*8 + r]);
  }
}

__global__ __launch_bounds__(256) void bf16_copy(
    const float* __restrict__ in, ushortt* __restrict__ out, size_t n) {
  for (size_t i = (size_t)blockIdx.x*256 + threadIdx.x; i < n; i += (size_t)gridDim.x*256)
    out[i] = f2bf(in[i]);
}

__global__ __launch_bounds__(256) void csa_kernel(
    const float* __restrict__ saWo, const float* __restrict__ sabin,
    const float* __restrict__ sabo, float* __restrict__ csa) {
  const int w = threadIdx.x >> 6, lane = threadIdx.x & 63;
  const int row = blockIdx.x*4 + w;
  const int l = row >> 9, f = row & 511;
  float acc = 0;
#pragma unroll
  for (int k = 0; k < 8; ++k) {
    int e = lane + 64*k;
    acc += saWo[((size_t)l*HS + f)*HS + e] * sabin[l*(3*HS) + 2*HS + e];
  }
  acc = wred(acc);
  if (lane == 0) csa[row] = acc + sabo[l*HS + f];
}

__global__ __launch_bounds__(256) void sqcbq_kernel(
    const float* __restrict__ caWin, const float* __restrict__ caBin,
    const float* __restrict__ lnG, const float* __restrict__ lnB,
    float* __restrict__ sq, float* __restrict__ cbq) {
  const int w = threadIdx.x >> 6, lane = threadIdx.x & 63;
  const int row = blockIdx.x*4 + w;
  const int l = row >> 9, f = row & 511;
  float a1 = 0, a2 = 0;
#pragma unroll
  for (int k = 0; k < 8; ++k) {
    int e = lane + 64*k;
    float wv = caWin[((size_t)l*(3*HS) + f)*HS + e];
    a1 += wv * lnG[l*(3*HS) + e];
    a2 += wv * lnB[l*(3*HS) + e];
  }
  a1 = wred(a1); a2 = wred(a2);
  if (lane == 0) { sq[row] = a1; cbq[row] = a2 + caBin[l*(3*HS) + f]; }
}

// ---------------- main persistent sequential kernel (R12 topology, bf16 gates) ----

__global__ __launch_bounds__(NT, 1) void seq_kernel(
    const float* __restrict__ x,
    const float* __restrict__ bx, const float* __restrict__ bh,
    const float* __restrict__ caBo,
    const float* __restrict__ ffB1,
    const float* __restrict__ ffB2,
    const float* __restrict__ lnG,  const float* __restrict__ lnB,
    float* __restrict__ ws, float* __restrict__ out) {
  const ushortt* Kb    = (const ushortt*)(ws + OFF_KBF);
  const ushortt* Vt    = (const ushortt*)(ws + OFF_VBF);
  const ushortt* Wcomb = (const ushortt*)(ws + OFF_WCOMBBF);
  const ushortt* WQP   = (const ushortt*)(ws + OFF_WQP);
  const ushortt* W2P   = (const ushortt*)(ws + OFF_W2P);
  const ushortt* F1b   = (const ushortt*)(ws + OFF_FFW1BF);
  const ushortt* CaWob = (const ushortt*)(ws + OFF_CAWOBF);
  const ushortt* WXb   = (const ushortt*)(ws + OFF_WXBF);
  const ushortt* WHb   = (const ushortt*)(ws + OFF_WHBF);
  const float* csag  = ws + OFF_CSA;
  const float* sqg   = ws + OFF_SQ;
  const float* cbqg  = ws + OFF_CBQ;
  float* hG    = ws + OFF_H;
  float* cG    = ws + OFF_C;
  float* xing  = ws + OFF_XING;
  float* z1g   = ws + OFF_Z1;
  float* z02g  = ws + OFF_Z02;
  float* t2g   = ws + OFF_T2G;
  float* Yp    = ws + OFF_YP;
  float* Y2p   = ws + OFF_Y2P;
  float* ctxP  = ws + OFF_CTXP;
  float* denS  = ws + OFF_DENS;
  float* s1s   = ws + OFF_S1S;
  float* s2s   = ws + OFF_S2S;
  unsigned* J1     = (unsigned*)(ws + OFF_J1);
  unsigned* J2     = (unsigned*)(ws + OFF_J2);
  unsigned* bflags = (unsigned*)(ws + OFF_FLAGS);

  __shared__ float sh_xin[HS], sh_h[HS], sh_vec[HS], sh_aux[HS];
  __shared__ float sh_q[128], sh_p[64], sh_t1[16];
  __shared__ float sh_red[24], sh_den[4];

  const int bid = blockIdx.x, tid = threadIdx.x;
  const int w = tid >> 6, lane = tid & 63;
  const int g4 = tid >> 7, dd = tid & 127;
  unsigned gen = 1;

  unsigned pZx[4],  pZh[4];       // z1 rows (bid<64), bf16 packed
  unsigned pZx2[4], pZh2[4];      // z0/z2 rows (bid<32 | bid>=160)
  unsigned pWc[2][4], pWq[8];     // H2 (bid<32)
  unsigned pK[2][4],  pV[8];      // H3 attn (32<=bid<160)
  unsigned pCa[2][4];             // H4 (bid<32)
  unsigned pF1[4], pW2[4];        // H5 (all)

  auto pfH1 = [&](int l) {
    if (bid < 64) {
      const size_t ro = (((size_t)l*3 + 1)*HS + bid*8 + w)*HS + lane*8;
      ld8bfp(WXb + ro, pZx);
      ld8bfp(WHb + ro, pZh);
    }
  };
  auto pfH2 = [&](int l) {
    if (bid < 32) {
#pragma unroll
      for (int rr = 0; rr < 2; ++rr)
        ld8bfp(Wcomb + ((size_t)l*HS + bid*16 + w*2 + rr)*HS + lane*8, pWc[rr]);
      const ushortt* q = WQP + (((size_t)l*32 + bid)*512 + tid)*16;
      ld8bfp(q,     pWq);
      ld8bfp(q + 8, pWq + 4);
    }
  };
  auto pfH3 = [&](int l) {
    if (bid >= 32 && bid < 160) {
      const int b2 = bid - 32, h = b2 >> 5, ms = b2 & 31;
#pragma unroll
      for (int rr = 0; rr < 2; ++rr)
        ld8bfp(Kb + ((size_t)l*MMEM + ms*64 + w*8 + (lane>>4) + 4*rr)*HS
                  + h*128 + (lane & 15)*8, pK[rr]);
      const ushortt* vp = Vt + (size_t)l*MMEM*HS
                        + ((size_t)h*128 + dd)*MMEM + ms*64 + g4*16;
      ld8bfp(vp,     pV);
      ld8bfp(vp + 8, pV + 4);
    }
  };
  auto pfZ = [&](int l) {
    if (bid < 32 || bid >= 160) {
      const int zb = (bid < 32) ? bid : bid - 128;
      const int rowid = zb*8 + w;
      const int g = (rowid < 512) ? 0 : 2;
      const int f = rowid & 511;
      const size_t ro = (((size_t)l*3 + g)*HS + f)*HS + lane*8;
      ld8bfp(WXb + ro, pZx2);
      ld8bfp(WHb + ro, pZh2);
    }
  };
  auto pfH4 = [&](int l) {
    if (bid < 32) {
#pragma unroll
      for (int rr = 0; rr < 2; ++rr)
        ld8bfp(CaWob + ((size_t)l*HS + bid*16 + w*2 + rr)*HS + lane*8, pCa[rr]);
    }
  };
  auto pfH5 = [&](int l) {
    ld8bfp(F1b + ((size_t)l*FFD + bid*8 + w)*HS + lane*8, pF1);
    ld8bfp(W2P + (((size_t)l*NB + bid)*512 + tid)*8, pW2);
  };

  auto do_update = [&](int ip, int parp, float& xn, float& cn) {
    const int j = tid;
    float t2v = ald(t2g + j);
    float z0  = ald(z02g + j);
    float z2  = ald(z02g + HS + j);
    float y2 = 0;
    {
      float yv[8];
#pragma unroll
      for (int p = 0; p < 8; ++p) yv[p] = ald(Y2p + (size_t)p*HS + j);
#pragma unroll
      for (int p = 0; p < 8; ++p) y2 += yv[p];
    }
    slotred32(s2s, sh_red, 16, w, lane);
    __syncthreads();
    float m2 = sh_red[16]*INV512;
    float r2 = rsqrtf(sh_red[17]*INV512 - m2*m2 + 1e-5f);
    float x2 = (t2v-m2)*r2*lnG[(ip*3+1)*HS+j] + lnB[(ip*3+1)*HS+j];
    float t3 = x2 + y2 + ffB2[ip*HS + j];
    float s_ = t3, q_ = t3*t3;
#pragma unroll
    for (int m = 32; m; m >>= 1) { s_ += __shfl_xor(s_, m); q_ += __shfl_xor(q_, m); }
    if (lane == 0) { sh_red[w] = s_; sh_red[8+w] = q_; }
    __syncthreads();
    if (tid == 0) {
      float a = 0, b = 0;
#pragma unroll
      for (int k = 0; k < 8; ++k) { a += sh_red[k]; b += sh_red[8+k]; }
      sh_red[0] = a; sh_red[1] = b;
    }
    __syncthreads();
    float m3 = sh_red[0]*INV512;
    float r3 = rsqrtf(sh_red[1]*INV512 - m3*m3 + 1e-5f);
    float d  = (t3-m3)*r3*lnG[(ip*3+2)*HS+j] + lnB[(ip*3+2)*HS+j];
    float cp = ald(cG + (parp*LNUM + ip)*HS + j);
    float ft = sigm(cp - d);
    float it = sigm(z0);
    float gt = tanhf(z2);
    cn = ft*cp + it*gt;
    xn = tanhf(cn);
  };

  pfH1(0); pfH2(0); pfH3(0);

  for (int s = 0; s < TT*LNUM; ++s) {
    const int t = s >> 2, i = s & 3;
    const int par = t & 1;
    const unsigned jv = (unsigned)(s + 1);
    // ---------- H1 window: update(s-1) + z1 matvec (0-63); zeroers (64-66) ----------
    if (bid < 64) {
      float xn = 0.f, cn = 0.f;
      if (s > 0) {
        const int ip = (s-1) & 3, tp = (s-1) >> 2, parp = tp & 1;
        if (bid == 0 || i > 0) {
          do_update(ip, parp, xn, cn);
          if (bid == 0) {
            ast(hG + ((parp^1)*LNUM + ip)*HS + tid, xn);
            ast(cG + ((parp^1)*LNUM + ip)*HS + tid, cn);
            if (ip == 3) out[tp*HS + tid] = xn;
          }
        }
      }
      float xv = (i == 0) ? x[t*HS + tid] : xn;
      sh_xin[tid] = xv;
      sh_h[tid]   = ald(hG + (par*LNUM + i)*HS + tid);
      if (bid == 0) ast(xing + tid, xv);
      __syncthreads();
      const int f = bid*8 + w;
      float acc = 0;
#pragma unroll
      for (int k = 0; k < 4; ++k) {
        unsigned px = pZx[k], ph = pZh[k];
        acc += bflo(px)*sh_xin[lane*8 + 2*k] + bfhi(px)*sh_xin[lane*8 + 2*k + 1]
             + bflo(ph)*sh_h[lane*8 + 2*k]  + bfhi(ph)*sh_h[lane*8 + 2*k + 1];
      }
      acc = wred(acc);
      if (lane == 0) ast(z1g + f, acc + bx[(i*3+1)*HS + f] + bh[(i*3+1)*HS + f]);
      jflag(J1, bid, jv);
    } else if (bid == 64) {
#pragma unroll
      for (int p = 0; p < 4; ++p) ast(Yp + (size_t)p*HS + tid, 0.f);
      jflag(J1, 64, jv);
    } else if (bid == 65) {
#pragma unroll
      for (int p = 0; p < 8; ++p) ast(ctxP + (size_t)p*HS + tid, 0.f);
    } else if (bid == 66) {
      jwait_pf(J1, 65, jv, [&]{});
#pragma unroll
      for (int p = 0; p < 8; ++p) ast(Y2p + (size_t)p*HS + tid, 0.f);
    }
    // ---------- J1 -> H2 (blocks 0-31): t1 + deferred q + stats1 slots ----------
    if (bid < 32) {
      jwait_pf(J1, 65, jv, [&]{});
      sh_vec[tid] = sigm(ald(z1g + tid));  // f0
      __syncthreads();
#pragma unroll
      for (int rr = 0; rr < 2; ++rr) {
        const int r = w*2 + rr, j = bid*16 + r;
        float acc = 0;
#pragma unroll
        for (int k = 0; k < 4; ++k) {
          unsigned pw = pWc[rr][k];
          acc += bflo(pw)*sh_vec[lane*8 + 2*k] + bfhi(pw)*sh_vec[lane*8 + 2*k + 1];
        }
        acc = wred(acc);
        if (lane == 0) {
          float t1v = sh_vec[j] + acc + csag[i*HS + j];
          sh_t1[r]  = t1v;
          sh_aux[r] = t1v;
        }
      }
      __syncthreads();
      {
        float yl = 0;
#pragma unroll
        for (int q = 0; q < 8; ++q) {
          unsigned pw = pWq[q];
          yl += sh_aux[2*q]*bflo(pw) + sh_aux[2*q+1]*bfhi(pw);
        }
        atomicAdd(&Yp[(size_t)(bid & 3)*HS + tid], yl);
      }
      if (w == 0 && lane < 16) {
        float v = sh_aux[lane], s_ = v, q_ = v*v;
#pragma unroll
        for (int m = 8; m; m >>= 1) { s_ += __shfl_xor(s_, m); q_ += __shfl_xor(q_, m); }
        if (lane == 0) { ast(s1s + bid*2, s_); ast(s1s + bid*2 + 1, q_); }
      }
    }
    barrier_pf(bflags, gen, [&]{ pfZ(i); pfH4(i); pfH5(i); });
    // ---------- H3 window: attention (32-159) | z0/z2 (0-31, 160-255) ----------
    if (bid >= 32 && bid < 160) {
      const int b2 = bid - 32, h = b2 >> 5;
      slotred32(s1s, sh_red, 18, w, lane);
      __syncthreads();
      if (tid < 128) {
        float m1 = sh_red[18]*INV512;
        float r1 = rsqrtf(sh_red[19]*INV512 - m1*m1 + 1e-5f);
        int f = h*128 + tid;
        float Ysum = 0;
#pragma unroll
        for (int p = 0; p < 4; ++p) Ysum += ald(Yp + (size_t)p*HS + f);
        sh_q[tid] = r1*(Ysum - m1*sqg[i*HS + f]) + cbqg[i*HS + f];
      }
      __syncthreads();
#pragma unroll
      for (int rr = 0; rr < 2; ++rr) {
        float sc = 0;
#pragma unroll
        for (int k = 0; k < 4; ++k) {
          unsigned pw = pK[rr][k];
          sc += bflo(pw)*sh_q[(lane & 15)*8 + 2*k] + bfhi(pw)*sh_q[(lane & 15)*8 + 2*k + 1];
        }
#pragma unroll
        for (int msk = 8; msk; msk >>= 1) sc += __shfl_xor(sc, msk);
        if ((lane & 15) == 0) sh_p[w*8 + (lane >> 4) + 4*rr] = __expf(sc * QSCALE);
      }
      __syncthreads();
      {   // ctx partial (Vt: 16 contiguous m per thread)
        const int d = tid & 127, mg = tid >> 7;
        float acc = 0;
#pragma unroll
        for (int q = 0; q < 8; ++q) {
          unsigned pw = pV[q];
          acc += sh_p[mg*16 + 2*q]*bflo(pw) + sh_p[mg*16 + 2*q + 1]*bfhi(pw);
        }
        atomicAdd(&ctxP[(size_t)((b2 & 1)*4 + mg)*HS + h*128 + d], acc);
      }
      if (w == 0) {
        float v = wred(sh_p[lane]);
        if (lane == 0) ast(denS + h*32 + (b2 & 31), v);
      }
      jflag(J2, b2, jv);
    } else {
      const int zb = (bid < 32) ? bid : bid - 128;
      if (bid >= 160) {
        sh_xin[tid] = ald(xing + tid);
        sh_h[tid]   = ald(hG + (par*LNUM + i)*HS + tid);
      }
      __syncthreads();
      const int rowid = zb*8 + w;
      const int g = (rowid < 512) ? 0 : 2;
      const int f = rowid & 511;
      float acc = 0;
#pragma unroll
      for (int k = 0; k < 4; ++k) {
        unsigned px = pZx2[k], ph = pZh2[k];
        acc += bflo(px)*sh_xin[lane*8 + 2*k] + bfhi(px)*sh_xin[lane*8 + 2*k + 1]
             + bflo(ph)*sh_h[lane*8 + 2*k]  + bfhi(ph)*sh_h[lane*8 + 2*k + 1];
      }
      acc = wred(acc);
      if (lane == 0) ast(z02g + (g ? HS : 0) + f, acc + bx[(i*3+g)*HS + f] + bh[(i*3+g)*HS + f]);
      // ---------- J2 -> H4 (blocks 0-31): t2 + stats2 slots ----------
      if (bid < 32) {
        jwait_pf(J2, 128, jv, [&]{});
        slotred32(s1s, sh_red, 18, w, lane);
        if (w >= 4) {
          float v = (lane < 32) ? ald(denS + (w-4)*32 + lane) : 0.f;
#pragma unroll
          for (int m = 16; m; m >>= 1) v += __shfl_xor(v, m);
          if (lane == 0) sh_den[w-4] = v;
        }
        __syncthreads();
        const float m1 = sh_red[18]*INV512;
        const float r1 = rsqrtf(sh_red[19]*INV512 - m1*m1 + 1e-5f);
        {
          float c = 0;
#pragma unroll
          for (int p = 0; p < 8; ++p) c += ald(ctxP + (size_t)p*HS + tid);
          sh_vec[tid] = c / sh_den[tid >> 7];
        }
        __syncthreads();
#pragma unroll
        for (int rr = 0; rr < 2; ++rr) {
          const int r = w*2 + rr, j = bid*16 + r;
          float a2 = 0;
#pragma unroll
          for (int k = 0; k < 4; ++k) {
            unsigned pw = pCa[rr][k];
            a2 += bflo(pw)*sh_vec[lane*8 + 2*k] + bfhi(pw)*sh_vec[lane*8 + 2*k + 1];
          }
          a2 = wred(a2);
          if (lane == 0) {
            float x1 = (sh_t1[r]-m1)*r1*lnG[(i*3)*HS + j] + lnB[(i*3)*HS + j];
            float t2v = x1 + a2 + caBo[i*HS + j];
            ast(t2g + j, t2v);
            sh_aux[r] = t2v;
          }
        }
        __syncthreads();
        if (w == 0 && lane < 16) {
          float v = sh_aux[lane], s_ = v, q_ = v*v;
#pragma unroll
          for (int m = 8; m; m >>= 1) { s_ += __shfl_xor(s_, m); q_ += __shfl_xor(q_, m); }
          if (lane == 0) { ast(s2s + bid*2, s_); ast(s2s + bid*2 + 1, q_); }
        }
      }
    }
    barrier_pf(bflags, gen+1, [&]{ const int nl = (s+1) & 3; pfH1(nl); pfH2(nl); pfH3(nl); });
    // ---------- H5: all blocks: ff1 = relu(W1@x2+b1); Y2 plane += W2T@ff1 ----------
    {
      slotred32(s2s, sh_red, 16, w, lane);
      __syncthreads();
      const float m2 = sh_red[16]*INV512;
      const float r2 = rsqrtf(sh_red[17]*INV512 - m2*m2 + 1e-5f);
      sh_vec[tid] = (ald(t2g + tid)-m2)*r2*lnG[(i*3+1)*HS + tid] + lnB[(i*3+1)*HS + tid];
      __syncthreads();
      const int kk = bid*8 + w;
      float acc = 0;
#pragma unroll
      for (int k = 0; k < 4; ++k) {
        unsigned pw = pF1[k];
        acc += bflo(pw)*sh_vec[lane*8 + 2*k] + bfhi(pw)*sh_vec[lane*8 + 2*k + 1];
      }
      acc = wred(acc);
      if (lane == 0) sh_aux[w] = fmaxf(acc + ffB1[i*FFD + kk], 0.f);
      __syncthreads();
      float yl = 0;
#pragma unroll
      for (int q = 0; q < 4; ++q) {
        unsigned pw = pW2[q];
        yl += sh_aux[2*q]*bflo(pw) + sh_aux[2*q+1]*bfhi(pw);
      }
      atomicAdd(&Y2p[(size_t)(bid & 7)*HS + tid], yl);
    }
    barrier_pf(bflags, gen+2, [&]{});
    gen += 3;
  }

  // ---------- epilogue: final update (t=127, i=3) + output assembly ----------
  if (bid == 0) {
    float xn, cn;
    do_update(3, 1, xn, cn);
    out[127*HS + tid] = xn;
    out[TT*HS + 3*HS + tid] = xn;                 // h_T[3]
    out[TT*HS + LNUM*HS + 3*HS + tid] = cn;       // c_T[3]
#pragma unroll
    for (int ii = 0; ii < 3; ++ii) {
      out[TT*HS + ii*HS + tid]            = ald(hG + (0*LNUM + ii)*HS + tid);
      out[TT*HS + LNUM*HS + ii*HS + tid]  = ald(cG + (0*LNUM + ii)*HS + tid);
    }
  }
}

// ---------------- host launcher ----------------
extern "C" void kernel_launch(void* const* d_in, const int* in_sizes, int n_in,
                              void* d_out, int out_size, void* d_ws, size_t ws_size,
                              hipStream_t stream) {
  const float* x      = (const float*)d_in[0];
  const float* hist   = (const float*)d_in[1];
  const float* Wx     = (const float*)d_in[2];
  const float* bx     = (const float*)d_in[3];
  const float* Wh     = (const float*)d_in[4];
  const float* bh     = (const float*)d_in[5];
  const float* saWin  = (const float*)d_in[6];
  const float* saBin  = (const float*)d_in[7];
  const float* saWo   = (const float*)d_in[8];
  const float* saBo   = (const float*)d_in[9];
  const float* caWin  = (const float*)d_in[10];
  const float* caBin  = (const float*)d_in[11];
  const float* caWo   = (const float*)d_in[12];
  const float* caBo   = (const float*)d_in[13];
  const float* ffW1   = (const float*)d_in[14];
  const float* ffB1   = (const float*)d_in[15];
  const float* ffW2   = (const float*)d_in[16];
  const float* ffB2   = (const float*)d_in[17];
  const float* lnG    = (const float*)d_in[18];
  const float* lnB    = (const float*)d_in[19];
  float* ws  = (float*)d_ws;
  float* out = (float*)d_out;

  hipMemsetAsync((char*)d_ws + OFF_STATE*sizeof(float), 0,
                 (WS_TOTAL - OFF_STATE)*sizeof(float), stream);

  kv_gemm<<<dim3(MMEM/64, HS/64, LNUM), 256, 0, stream>>>(
      hist, caWin, caBin, (ushortt*)(ws + OFF_KBF), HS, 0);
  kv_gemm<<<dim3(MMEM/64, HS/64, LNUM), 256, 0, stream>>>(
      hist, caWin, caBin, (ushortt*)(ws + OFF_VBF), 2*HS, 1);
  wcomb_gemm<<<dim3(HS/64, HS/64, LNUM), 256, 0, stream>>>(
      saWo, saWin, (ushortt*)(ws + OFF_WCOMBBF));
  csa_kernel<<<(LNUM*HS)/4, 256, 0, stream>>>(saWo, saBin, saBo, ws + OFF_CSA);
  pack_wq<<<dim3(32, LNUM), 256, 0, stream>>>(caWin, lnG, (ushortt*)(ws + OFF_WQP));
  sqcbq_kernel<<<(LNUM*HS)/4, 256, 0, stream>>>(caWin, caBin, lnG, lnB, ws + OFF_SQ, ws + OFF_CBQ);
  pack_w2<<<dim3(NB, LNUM), 256, 0, stream>>>(ffW2, (ushortt*)(ws + OFF_W2P));
  bf16_copy<<<2048, 256, 0, stream>>>(ffW1, (ushortt*)(ws + OFF_FFW1BF), (size_t)LNUM*FFD*HS);
  bf16_copy<<<1024, 256, 0, stream>>>(caWo, (ushortt*)(ws + OFF_CAWOBF), (size_t)LNUM*HS*HS);
  bf16_copy<<<2048, 256, 0, stream>>>(Wx, (ushortt*)(ws + OFF_WXBF), (size_t)LNUM*3*HS*HS);
  bf16_copy<<<2048, 256, 0, stream>>>(Wh, (ushortt*)(ws + OFF_WHBF), (size_t)LNUM*3*HS*HS);

  seq_kernel<<<NB, NT, 0, stream>>>(x, bx, bh, caBo,
                                    ffB1, ffB2, lnG, lnB, ws, out);
}